// Round 13
// baseline (78.093 us; speedup 1.0000x reference)
//
#include <hip/hip_runtime.h>

// RBF Gram via single-pass fp16 MFMA with quantization-cancelling norms.
//   P1: x (fp32 [N][64]) -> H (fp16, XOR-swizzled per 128-row chunk), sq = ||fp16(x)||^2.
//       Same quantized vectors for norms and dots => kernel computes exactly
//       ||h_i-h_j||^2 (fp16 products exact in fp32) -> error ~0 where exp() matters.
//   P2: each block owns a 128x512 strip: A panel staged once, 4 B-tiles pipelined
//       with RAW s_barrier + lgkmcnt-only waits so output stores are NEVER drained
//       mid-loop (vmcnt stays counted; compiler waits only the 4 prefetch loads).
//       1024 blocks = 4/CU all-resident. Swapped-operand MFMA (D^T) -> dwordx4 stores.

#define GAMMA 0.5f
#define TJ 4

typedef __attribute__((ext_vector_type(8))) _Float16 half8;
typedef __attribute__((ext_vector_type(4))) float f32x4;

// ---------------- Phase 1: fp16 quantize + swizzle + quantized norms ----------------
__global__ __launch_bounds__(256) void quant_kernel(const float* __restrict__ x,
                                                    unsigned short* __restrict__ H,
                                                    float* __restrict__ sq) {
    int tid = blockIdx.x * 256 + threadIdx.x;   // one float4 (4 elems of one row)
    int row = tid >> 4, c4 = tid & 15;
    float4 v = ((const float4*)x)[tid];
    float e[4] = {v.x, v.y, v.z, v.w};
    unsigned short hb[4];
    float s = 0.f;
    #pragma unroll
    for (int i = 0; i < 4; ++i) {
        _Float16 h = (_Float16)e[i];            // RNE
        float hf = (float)h;
        s = fmaf(hf, hf, s);                    // norm of the QUANTIZED vector
        hb[i] = __builtin_bit_cast(unsigned short, h);
    }
    int rr = row & 127;
    size_t base = (size_t)(row >> 7) * 16384;
    int b = (rr * 128 + c4 * 8) ^ ((rr & 7) << 4);
    uint2 hw = {(unsigned)hb[0] | ((unsigned)hb[1] << 16),
                (unsigned)hb[2] | ((unsigned)hb[3] << 16)};
    *(uint2*)((char*)H + base + b) = hw;
    s += __shfl_xor(s, 1); s += __shfl_xor(s, 2);
    s += __shfl_xor(s, 4); s += __shfl_xor(s, 8);
    if (c4 == 0) sq[row] = s;
}

// ---------------- Phase 2: 128x512 strip per block, pipelined tiles ----------------
__global__ __launch_bounds__(256, 4) void rbf_mfma8(const unsigned short* __restrict__ H,
                                                    const float* __restrict__ sq,
                                                    float* __restrict__ out, int N) {
    __shared__ unsigned short Ah[8192], Bh[8192];   // 16 KB + 16 KB = 32 KB

    const int tid = threadIdx.x;
    const int i0 = blockIdx.y * 128;
    const int j0b = blockIdx.x * (128 * TJ);
    const int w = tid >> 6, lane = tid & 63;
    const int fr = lane & 15, kg = lane >> 4;
    const int wr = (w >> 1) * 64, wc = (w & 1) * 64;   // wave quadrant of 128x128

    // ---- stage A panel (once) + B tile 0; swizzle pre-baked in global layout ----
    {
        const uint4* ga = (const uint4*)(H + (size_t)i0 * 64);
        const uint4* gb = (const uint4*)(H + (size_t)j0b * 64);
        #pragma unroll
        for (int t = 0; t < 4; ++t) {
            ((uint4*)Ah)[t * 256 + tid] = ga[t * 256 + tid];
            ((uint4*)Bh)[t * 256 + tid] = gb[t * 256 + tid];
        }
    }
    __syncthreads();   // full barrier OK here (no output stores outstanding yet)

    for (int tj = 0; tj < TJ; ++tj) {
        const int j0 = j0b + tj * 128;

        // ---- K-loop: 2 ksteps, swapped operands -> D^T ----
        f32x4 acc[4][4];
        #pragma unroll
        for (int p = 0; p < 4; ++p)
            #pragma unroll
            for (int q = 0; q < 4; ++q) acc[p][q] = (f32x4)(0.f);

        #pragma unroll
        for (int ks = 0; ks < 2; ++ks) {
            const int kb = ks * 64 + kg * 16;
            half8 ah[4], bh[4];
            #pragma unroll
            for (int p = 0; p < 4; ++p) {
                int R = wr + p * 16 + fr;
                int off = (R * 128 + kb) ^ ((R & 7) << 4);
                ah[p] = *(const half8*)((const char*)Ah + off);
            }
            #pragma unroll
            for (int q = 0; q < 4; ++q) {
                int R = wc + q * 16 + fr;
                int off = (R * 128 + kb) ^ ((R & 7) << 4);
                bh[q] = *(const half8*)((const char*)Bh + off);
            }
            #pragma unroll
            for (int p = 0; p < 4; ++p)
                #pragma unroll
                for (int q = 0; q < 4; ++q)
                    acc[p][q] = __builtin_amdgcn_mfma_f32_16x16x32_f16(bh[q], ah[p], acc[p][q], 0, 0, 0);
        }

        // ---- T14 prefetch: issue next B-tile global loads BEFORE the store burst,
        //      so the compiler's precise vmcnt wait for pb covers only these 4 loads.
        uint4 pb[4];
        if (tj + 1 < TJ) {
            const uint4* gb = (const uint4*)(H + (size_t)(j0 + 128) * 64);
            #pragma unroll
            for (int t = 0; t < 4; ++t) pb[t] = gb[t * 256 + tid];
        }

        // ---- epilogue: D^T => lane holds row (i0+wr+p*16+fr), cols (wc+q*16+kg*4..+3)
        #pragma unroll
        for (int p = 0; p < 4; ++p) {
            int ri = wr + p * 16 + fr;
            float sa = sq[i0 + ri];
            float* rowp = out + (size_t)(i0 + ri) * N + j0;
            #pragma unroll
            for (int q = 0; q < 4; ++q) {
                int c = wc + q * 16 + kg * 4;
                float4 sb = *(const float4*)&sq[j0 + c];
                f32x4 a = acc[p][q];
                float4 r;
                r.x = __expf(-GAMMA * fmaxf(fmaf(-2.f, a[0], sa + sb.x), 0.f));
                r.y = __expf(-GAMMA * fmaxf(fmaf(-2.f, a[1], sa + sb.y), 0.f));
                r.z = __expf(-GAMMA * fmaxf(fmaf(-2.f, a[2], sa + sb.z), 0.f));
                r.w = __expf(-GAMMA * fmaxf(fmaf(-2.f, a[3], sa + sb.w), 0.f));
                *(float4*)(rowp + c) = r;
            }
        }

        // ---- LDS-only barriers (raw s_barrier, lgkmcnt-only): stores stay in flight
        if (tj + 1 < TJ) {
            asm volatile("s_waitcnt lgkmcnt(0)" ::: "memory");  // my ds_reads of tile tj done
            __builtin_amdgcn_sched_barrier(0);
            __builtin_amdgcn_s_barrier();                        // all waves done reading Bh
            __builtin_amdgcn_sched_barrier(0);
            #pragma unroll
            for (int t = 0; t < 4; ++t)                          // regs -> LDS (waits pb only)
                ((uint4*)Bh)[t * 256 + tid] = pb[t];
            asm volatile("s_waitcnt lgkmcnt(0)" ::: "memory");   // my ds_writes visible
            __builtin_amdgcn_sched_barrier(0);
            __builtin_amdgcn_s_barrier();                        // all waves' Bh ready
            __builtin_amdgcn_sched_barrier(0);
        }
    }
}

extern "C" void kernel_launch(void* const* d_in, const int* in_sizes, int n_in,
                              void* d_out, int out_size, void* d_ws, size_t ws_size,
                              hipStream_t stream) {
    (void)n_in; (void)ws_size; (void)out_size;
    const float* x = (const float*)d_in[0];
    float* out = (float*)d_out;
    const int K = 64;
    const int N = in_sizes[0] / K;   // 8192

    unsigned short* H = (unsigned short*)d_ws;       // N*64 fp16 = 1 MB
    float* sq = (float*)(H + (size_t)N * K);         // 32 KB

    quant_kernel<<<dim3(N * K / 4 / 256), dim3(256), 0, stream>>>(x, H, sq);
    // grid: 16 x 64 = 1024 blocks = 4/CU, all resident (zero turnover)
    rbf_mfma8<<<dim3(N / (128 * TJ), N / 128), dim3(256), 0, stream>>>(H, sq, out, N);
}

// Round 14
// 63.787 us; speedup vs baseline: 1.2243x; 1.2243x over previous
//
#include <hip/hip_runtime.h>

// RBF Gram via single-pass fp16 MFMA with quantization-cancelling norms.
//   P1: x (fp32 [N][64]) -> H (fp16, XOR-swizzled per 128-row chunk), sq = ||fp16(x)||^2.
//       Same quantized vectors for norms and dots => kernel computes exactly
//       ||h_i-h_j||^2 (fp16 products exact in fp32) -> error ~0 where exp() matters.
//   P2: each block owns a 128x512 strip. Stage A (16KB) + ALL 4 B-tiles (64KB)
//       up front (80 KB LDS, 2 blocks/CU), ONE barrier, then compute+store the
//       4 tiles back-to-back with ZERO barriers: tile t's stores drain in the
//       background under tile t+1's ds_reads/MFMA (in-order wave, non-blocking
//       stores; vmcnt backpressure is the only throttle = write-bound steady state).

#define GAMMA 0.5f
#define TJ 4

typedef __attribute__((ext_vector_type(8))) _Float16 half8;
typedef __attribute__((ext_vector_type(4))) float f32x4;

// ---------------- Phase 1: fp16 quantize + swizzle + quantized norms ----------------
__global__ __launch_bounds__(256) void quant_kernel(const float* __restrict__ x,
                                                    unsigned short* __restrict__ H,
                                                    float* __restrict__ sq) {
    int tid = blockIdx.x * 256 + threadIdx.x;   // one float4 (4 elems of one row)
    int row = tid >> 4, c4 = tid & 15;
    float4 v = ((const float4*)x)[tid];
    float e[4] = {v.x, v.y, v.z, v.w};
    unsigned short hb[4];
    float s = 0.f;
    #pragma unroll
    for (int i = 0; i < 4; ++i) {
        _Float16 h = (_Float16)e[i];            // RNE
        float hf = (float)h;
        s = fmaf(hf, hf, s);                    // norm of the QUANTIZED vector
        hb[i] = __builtin_bit_cast(unsigned short, h);
    }
    int rr = row & 127;
    size_t base = (size_t)(row >> 7) * 16384;
    int b = (rr * 128 + c4 * 8) ^ ((rr & 7) << 4);
    uint2 hw = {(unsigned)hb[0] | ((unsigned)hb[1] << 16),
                (unsigned)hb[2] | ((unsigned)hb[3] << 16)};
    *(uint2*)((char*)H + base + b) = hw;
    s += __shfl_xor(s, 1); s += __shfl_xor(s, 2);
    s += __shfl_xor(s, 4); s += __shfl_xor(s, 8);
    if (c4 == 0) sq[row] = s;
}

// ---------------- Phase 2: 128x512 strip, stage-all, zero mid-loop barriers ----------------
__global__ __launch_bounds__(256) void rbf_mfma9(const unsigned short* __restrict__ H,
                                                 const float* __restrict__ sq,
                                                 float* __restrict__ out, int N) {
    __shared__ unsigned short Ah[8192];        // 16 KB
    __shared__ unsigned short Bh[TJ * 8192];   // 64 KB  (4 tiles)

    const int tid = threadIdx.x;
    const int i0 = blockIdx.y * 128;
    const int j0b = blockIdx.x * (128 * TJ);
    const int w = tid >> 6, lane = tid & 63;
    const int fr = lane & 15, kg = lane >> 4;
    const int wr = (w >> 1) * 64, wc = (w & 1) * 64;   // wave quadrant of 128x128

    // ---- stage A + all 4 B tiles (swizzle pre-baked in global layout) ----
    {
        const uint4* ga = (const uint4*)(H + (size_t)i0 * 64);
        const uint4* gb = (const uint4*)(H + (size_t)j0b * 64);
        #pragma unroll
        for (int t = 0; t < 4; ++t)
            ((uint4*)Ah)[t * 256 + tid] = ga[t * 256 + tid];
        #pragma unroll
        for (int t = 0; t < 4 * TJ; ++t)
            ((uint4*)Bh)[t * 256 + tid] = gb[t * 256 + tid];
    }
    __syncthreads();   // the ONLY barrier

    for (int tj = 0; tj < TJ; ++tj) {
        const int j0 = j0b + tj * 128;
        const unsigned short* Bt = Bh + tj * 8192;

        // ---- K-loop: 2 ksteps, swapped operands -> D^T ----
        f32x4 acc[4][4];
        #pragma unroll
        for (int p = 0; p < 4; ++p)
            #pragma unroll
            for (int q = 0; q < 4; ++q) acc[p][q] = (f32x4)(0.f);

        #pragma unroll
        for (int ks = 0; ks < 2; ++ks) {
            const int kb = ks * 64 + kg * 16;
            half8 ah[4], bh[4];
            #pragma unroll
            for (int p = 0; p < 4; ++p) {
                int R = wr + p * 16 + fr;
                int off = (R * 128 + kb) ^ ((R & 7) << 4);
                ah[p] = *(const half8*)((const char*)Ah + off);
            }
            #pragma unroll
            for (int q = 0; q < 4; ++q) {
                int R = wc + q * 16 + fr;
                int off = (R * 128 + kb) ^ ((R & 7) << 4);
                bh[q] = *(const half8*)((const char*)Bt + off);
            }
            #pragma unroll
            for (int p = 0; p < 4; ++p)
                #pragma unroll
                for (int q = 0; q < 4; ++q)
                    acc[p][q] = __builtin_amdgcn_mfma_f32_16x16x32_f16(bh[q], ah[p], acc[p][q], 0, 0, 0);
        }

        // ---- epilogue: D^T => lane holds row (i0+wr+p*16+fr), cols (wc+q*16+kg*4..+3)
        #pragma unroll
        for (int p = 0; p < 4; ++p) {
            int ri = wr + p * 16 + fr;
            float sa = sq[i0 + ri];
            float* rowp = out + (size_t)(i0 + ri) * N + j0;
            #pragma unroll
            for (int q = 0; q < 4; ++q) {
                int c = wc + q * 16 + kg * 4;
                float4 sb = *(const float4*)&sq[j0 + c];
                f32x4 a = acc[p][q];
                float4 r;
                r.x = __expf(-GAMMA * fmaxf(fmaf(-2.f, a[0], sa + sb.x), 0.f));
                r.y = __expf(-GAMMA * fmaxf(fmaf(-2.f, a[1], sa + sb.y), 0.f));
                r.z = __expf(-GAMMA * fmaxf(fmaf(-2.f, a[2], sa + sb.z), 0.f));
                r.w = __expf(-GAMMA * fmaxf(fmaf(-2.f, a[3], sa + sb.w), 0.f));
                *(float4*)(rowp + c) = r;
            }
        }
        // no barrier: stores drain under next tile's ds_reads/MFMA
    }
}

extern "C" void kernel_launch(void* const* d_in, const int* in_sizes, int n_in,
                              void* d_out, int out_size, void* d_ws, size_t ws_size,
                              hipStream_t stream) {
    (void)n_in; (void)ws_size; (void)out_size;
    const float* x = (const float*)d_in[0];
    float* out = (float*)d_out;
    const int K = 64;
    const int N = in_sizes[0] / K;   // 8192

    unsigned short* H = (unsigned short*)d_ws;       // N*64 fp16 = 1 MB
    float* sq = (float*)(H + (size_t)N * K);         // 32 KB

    quant_kernel<<<dim3(N * K / 4 / 256), dim3(256), 0, stream>>>(x, H, sq);
    // grid: 16 x 64 = 1024 blocks, 80 KB LDS -> 2 blocks/CU
    rbf_mfma9<<<dim3(N / (128 * TJ), N / 128), dim3(256), 0, stream>>>(H, sq, out, N);
}

// Round 15
// 54.121 us; speedup vs baseline: 1.4429x; 1.1786x over previous
//
#include <hip/hip_runtime.h>

// RBF Gram via single-pass fp16 MFMA with quantization-cancelling norms.
//   P1: x (fp32 [N][64]) -> H (fp16, XOR-swizzled per 128-row chunk), sq = ||fp16(x)||^2.
//   P2: 128x128 tile, 4 waves; wave w owns rows w*32..w*32+31 x all 128 cols
//       (p=0..1 row-frags, q=0..7 col-frags). After MFMA: exp -> wave-private
//       8KB LDS bounce (reusing Ah/Bh, one barrier) -> readback so each store
//       instr writes 2 FULL ROWS x 512B contiguous (vs 16 x 64B scatter before).

#define GAMMA 0.5f

typedef __attribute__((ext_vector_type(8))) _Float16 half8;
typedef __attribute__((ext_vector_type(4))) float f32x4;

// ---------------- Phase 1: fp16 quantize + swizzle + quantized norms ----------------
__global__ __launch_bounds__(256) void quant_kernel(const float* __restrict__ x,
                                                    unsigned short* __restrict__ H,
                                                    float* __restrict__ sq) {
    int tid = blockIdx.x * 256 + threadIdx.x;   // one float4 (4 elems of one row)
    int row = tid >> 4, c4 = tid & 15;
    float4 v = ((const float4*)x)[tid];
    float e[4] = {v.x, v.y, v.z, v.w};
    unsigned short hb[4];
    float s = 0.f;
    #pragma unroll
    for (int i = 0; i < 4; ++i) {
        _Float16 h = (_Float16)e[i];            // RNE
        float hf = (float)h;
        s = fmaf(hf, hf, s);                    // norm of the QUANTIZED vector
        hb[i] = __builtin_bit_cast(unsigned short, h);
    }
    int rr = row & 127;
    size_t base = (size_t)(row >> 7) * 16384;
    int b = (rr * 128 + c4 * 8) ^ ((rr & 7) << 4);
    uint2 hw = {(unsigned)hb[0] | ((unsigned)hb[1] << 16),
                (unsigned)hb[2] | ((unsigned)hb[3] << 16)};
    *(uint2*)((char*)H + base + b) = hw;
    s += __shfl_xor(s, 1); s += __shfl_xor(s, 2);
    s += __shfl_xor(s, 4); s += __shfl_xor(s, 8);
    if (c4 == 0) sq[row] = s;
}

// ---------------- Phase 2: 128x128 tile, row-run stores via LDS bounce ----------------
__global__ __launch_bounds__(256, 4) void rbf_mfma10(const unsigned short* __restrict__ H,
                                                     const float* __restrict__ sq,
                                                     float* __restrict__ out, int N) {
    __shared__ __align__(16) char smem[32768];
    unsigned short* Ah = (unsigned short*)smem;             // 16 KB
    unsigned short* Bh = (unsigned short*)(smem + 16384);   // 16 KB
    // after the post-K barrier, smem is reused as 4 x 8KB wave-private bounce buffers

    const int tid = threadIdx.x;
    const int i0 = blockIdx.y * 128, j0 = blockIdx.x * 128;
    const int w = tid >> 6, lane = tid & 63;
    const int fr = lane & 15, kg = lane >> 4;
    const int wr = w * 32;                      // wave owns rows wr..wr+31, all 128 cols

    // ---- stage: linear 32KB copy (swizzle pre-baked in global layout) ----
    {
        const uint4* ga = (const uint4*)(H + (size_t)i0 * 64);
        const uint4* gb = (const uint4*)(H + (size_t)j0 * 64);
        #pragma unroll
        for (int t = 0; t < 4; ++t) {
            ((uint4*)Ah)[t * 256 + tid] = ga[t * 256 + tid];
            ((uint4*)Bh)[t * 256 + tid] = gb[t * 256 + tid];
        }
    }
    __syncthreads();

    // ---- K-loop: 2 ksteps, swapped operands -> D^T; acc[p][q] = rows x col-frags ----
    f32x4 acc[2][8];
    #pragma unroll
    for (int p = 0; p < 2; ++p)
        #pragma unroll
        for (int q = 0; q < 8; ++q) acc[p][q] = (f32x4)(0.f);

    #pragma unroll
    for (int ks = 0; ks < 2; ++ks) {
        const int kb = ks * 64 + kg * 16;
        half8 ah[2], bh[8];
        #pragma unroll
        for (int p = 0; p < 2; ++p) {
            int R = wr + p * 16 + fr;
            int off = (R * 128 + kb) ^ ((R & 7) << 4);
            ah[p] = *(const half8*)((const char*)Ah + off);
        }
        #pragma unroll
        for (int q = 0; q < 8; ++q) {
            int R = q * 16 + fr;
            int off = (R * 128 + kb) ^ ((R & 7) << 4);
            bh[q] = *(const half8*)((const char*)Bh + off);
        }
        #pragma unroll
        for (int p = 0; p < 2; ++p)
            #pragma unroll
            for (int q = 0; q < 8; ++q)
                acc[p][q] = __builtin_amdgcn_mfma_f32_16x16x32_f16(bh[q], ah[p], acc[p][q], 0, 0, 0);
    }

    __syncthreads();   // all waves done reading Ah/Bh; smem becomes bounce space
    float* wbuf = (float*)smem + w * 2048;      // wave-private 8 KB (16 rows x 128 cols)

    #pragma unroll
    for (int p = 0; p < 2; ++p) {
        // exp + swizzled ds_write: lane (fr,kg) holds rows p*16+fr, cols q*16+kg*4..+3
        float sa = sq[i0 + wr + p * 16 + fr];
        #pragma unroll
        for (int q = 0; q < 8; ++q) {
            int c = q * 16 + kg * 4;
            float4 sb = *(const float4*)&sq[j0 + c];
            f32x4 a = acc[p][q];
            float4 r;
            r.x = __expf(-GAMMA * fmaxf(fmaf(-2.f, a[0], sa + sb.x), 0.f));
            r.y = __expf(-GAMMA * fmaxf(fmaf(-2.f, a[1], sa + sb.y), 0.f));
            r.z = __expf(-GAMMA * fmaxf(fmaf(-2.f, a[2], sa + sb.z), 0.f));
            r.w = __expf(-GAMMA * fmaxf(fmaf(-2.f, a[3], sa + sb.w), 0.f));
            *(float4*)&wbuf[fr * 128 + (c ^ ((fr & 7) << 2))] = r;
        }
        // readback + store: 2 full rows x 512B contiguous per instruction
        // (same-wave RAW/WAR through wbuf ordered by compiler-inserted lgkmcnt waits)
        const int half = lane >> 5, lc = lane & 31;
        #pragma unroll
        for (int i = 0; i < 8; ++i) {
            int rl = i * 2 + half;              // row_local 0..15
            float4 v = *(const float4*)&wbuf[rl * 128 + ((lc * 4) ^ ((rl & 7) << 2))];
            int grow = i0 + wr + p * 16 + rl;
            *(float4*)(out + (size_t)grow * N + j0 + lc * 4) = v;
        }
    }
}

extern "C" void kernel_launch(void* const* d_in, const int* in_sizes, int n_in,
                              void* d_out, int out_size, void* d_ws, size_t ws_size,
                              hipStream_t stream) {
    (void)n_in; (void)ws_size; (void)out_size;
    const float* x = (const float*)d_in[0];
    float* out = (float*)d_out;
    const int K = 64;
    const int N = in_sizes[0] / K;   // 8192

    unsigned short* H = (unsigned short*)d_ws;       // N*64 fp16 = 1 MB
    float* sq = (float*)(H + (size_t)N * K);         // 32 KB

    quant_kernel<<<dim3(N * K / 4 / 256), dim3(256), 0, stream>>>(x, H, sq);
    rbf_mfma10<<<dim3(N / 128, N / 128), dim3(256), 0, stream>>>(H, sq, out, N);
}